// Round 1
// baseline (7056.100 us; speedup 1.0000x reference)
//
#include <hip/hip_runtime.h>
#include <math.h>

#define N_NODES 100000
#define N_EDGES 1600000
#define F_IN    512
#define HID     128
#define NCLS    64
#define NLAYERS 8

// ---------------- degree / norm ----------------

__global__ __launch_bounds__(256) void deg_init(float* __restrict__ deg) {
    int i = blockIdx.x * 256 + threadIdx.x;
    if (i < N_NODES) deg[i] = 1.0f;   // self-loop contributes 1
}

__global__ __launch_bounds__(256) void deg_count(const int* __restrict__ dst,
                                                 float* __restrict__ deg) {
    int e = blockIdx.x * 256 + threadIdx.x;
    if (e < N_EDGES) atomicAdd(&deg[dst[e]], 1.0f);
}

__global__ __launch_bounds__(256) void deg_to_dinv(float* __restrict__ deg) {
    int i = blockIdx.x * 256 + threadIdx.x;
    if (i < N_NODES) deg[i] = rsqrtf(deg[i]);   // deg >= 1 always
}

// ---------------- input GEMM: h = x @ w_in + b_in ; h0 = h ----------------
// 16 nodes per block, 256 threads: tx = col (0..127), ty = row-group (0..1),
// 8 rows per thread. x tile staged in LDS (32 KB).

__global__ __launch_bounds__(256) void in_gemm(const float* __restrict__ x,
                                               const float* __restrict__ w,
                                               const float* __restrict__ b,
                                               float* __restrict__ h,
                                               float* __restrict__ h0) {
    __shared__ float xs[16][F_IN];
    int block0 = blockIdx.x * 16;
    int tid = threadIdx.x;

    // cooperative load of 16x512 floats = 2048 float4, 8 per thread
    const float4* xg = (const float4*)(x + (size_t)block0 * F_IN);
    float4* xs4 = (float4*)&xs[0][0];
#pragma unroll
    for (int i = 0; i < 8; i++) xs4[tid + 256 * i] = xg[tid + 256 * i];
    __syncthreads();

    int col = tid & 127;
    int rg  = tid >> 7;   // 0..1
    float acc[8];
    float bb = b[col];
#pragma unroll
    for (int r = 0; r < 8; r++) acc[r] = bb;

    for (int k = 0; k < F_IN; k += 4) {
        float w0 = w[(k + 0) * HID + col];
        float w1 = w[(k + 1) * HID + col];
        float w2 = w[(k + 2) * HID + col];
        float w3 = w[(k + 3) * HID + col];
#pragma unroll
        for (int r = 0; r < 8; r++) {
            float4 xv = *(const float4*)&xs[rg * 8 + r][k];
            acc[r] += xv.x * w0 + xv.y * w1 + xv.z * w2 + xv.w * w3;
        }
    }
#pragma unroll
    for (int r = 0; r < 8; r++) {
        size_t idx = (size_t)(block0 + rg * 8 + r) * HID + col;
        h[idx]  = acc[r];
        h0[idx] = acc[r];
    }
}

// ---------------- SpMM (atomic scatter): agg[dst] += norm * h[src] ----------------
// blockDim = (128, 2): 2 edges per block, thread x = feature.

__global__ __launch_bounds__(256) void spmm_atomic(const int* __restrict__ srcI,
                                                   const int* __restrict__ dstI,
                                                   const float* __restrict__ dinv,
                                                   const float* __restrict__ h,
                                                   float* __restrict__ agg) {
    int e = blockIdx.x * 2 + threadIdx.y;
    int f = threadIdx.x;
    int s = srcI[e];
    int d = dstI[e];
    float nrm = dinv[s] * dinv[d];
    atomicAdd(&agg[(size_t)d * HID + f], nrm * h[(size_t)s * HID + f]);
}

// ---------------- per-layer: s = 0.9*(agg + dinv^2*h) + 0.1*h0 ;
//                  h = elu((1-beta)*s + beta*(s @ W)) ----------------
// 16 nodes per block, 256 threads, s tile computed on the fly into LDS.

__global__ __launch_bounds__(256) void layer_kernel(const float* __restrict__ agg,
                                                    const float* __restrict__ h0,
                                                    const float* __restrict__ dinv,
                                                    const float* __restrict__ W,
                                                    float* __restrict__ h,
                                                    float oneMinusBeta, float beta) {
    __shared__ float ss[16][HID];
    int block0 = blockIdx.x * 16;
    int tid = threadIdx.x;

    {
        const float4* aggv = (const float4*)(agg + (size_t)block0 * HID);
        const float4* hv   = (const float4*)(h   + (size_t)block0 * HID);
        const float4* h0v  = (const float4*)(h0  + (size_t)block0 * HID);
        float4* ssv = (float4*)&ss[0][0];
#pragma unroll
        for (int i = 0; i < 2; i++) {
            int idx  = tid + 256 * i;      // float4 index within tile (512 total)
            int node = idx >> 5;           // 32 float4 per row
            float dd = dinv[block0 + node];
            float d2 = dd * dd;
            float4 a  = aggv[idx];
            float4 hh = hv[idx];
            float4 z  = h0v[idx];
            float4 s4;
            s4.x = 0.9f * (a.x + d2 * hh.x) + 0.1f * z.x;
            s4.y = 0.9f * (a.y + d2 * hh.y) + 0.1f * z.y;
            s4.z = 0.9f * (a.z + d2 * hh.z) + 0.1f * z.z;
            s4.w = 0.9f * (a.w + d2 * hh.w) + 0.1f * z.w;
            ssv[idx] = s4;
        }
    }
    __syncthreads();

    int col = tid & 127;
    int rg  = tid >> 7;
    float acc[8] = {0.f, 0.f, 0.f, 0.f, 0.f, 0.f, 0.f, 0.f};

    for (int k = 0; k < HID; k += 4) {
        float w0 = W[(k + 0) * HID + col];
        float w1 = W[(k + 1) * HID + col];
        float w2 = W[(k + 2) * HID + col];
        float w3 = W[(k + 3) * HID + col];
#pragma unroll
        for (int r = 0; r < 8; r++) {
            float4 sv = *(const float4*)&ss[rg * 8 + r][k];
            acc[r] += sv.x * w0 + sv.y * w1 + sv.z * w2 + sv.w * w3;
        }
    }
#pragma unroll
    for (int r = 0; r < 8; r++) {
        int row = rg * 8 + r;
        float v = oneMinusBeta * ss[row][col] + beta * acc[r];
        v = (v > 0.f) ? v : (expf(v) - 1.0f);   // ELU
        h[(size_t)(block0 + row) * HID + col] = v;
    }
}

// ---------------- output: logits = h @ w_out + b_out ; log_softmax ----------------
// one wave (64 lanes = 64 classes) per node, 4 nodes per block.

__global__ __launch_bounds__(256) void out_kernel(const float* __restrict__ h,
                                                  const float* __restrict__ w,
                                                  const float* __restrict__ b,
                                                  float* __restrict__ out) {
    int node = blockIdx.x * 4 + (threadIdx.x >> 6);
    int lane = threadIdx.x & 63;
    const float* hr = h + (size_t)node * HID;
    float acc = b[lane];
    for (int k = 0; k < HID; k++) acc += hr[k] * w[k * NCLS + lane];
    // max over 64 lanes
    float m = acc;
#pragma unroll
    for (int off = 32; off; off >>= 1) m = fmaxf(m, __shfl_xor(m, off, 64));
    float ex = expf(acc - m);
    float ssum = ex;
#pragma unroll
    for (int off = 32; off; off >>= 1) ssum += __shfl_xor(ssum, off, 64);
    out[(size_t)node * NCLS + lane] = acc - m - logf(ssum);
}

// ---------------- launch ----------------

extern "C" void kernel_launch(void* const* d_in, const int* in_sizes, int n_in,
                              void* d_out, int out_size, void* d_ws, size_t ws_size,
                              hipStream_t stream) {
    const float* x      = (const float*)d_in[0];
    const int*   ei     = (const int*)  d_in[1];
    const float* w_in   = (const float*)d_in[2];
    const float* b_in   = (const float*)d_in[3];
    const float* conv_w = (const float*)d_in[4];
    const float* w_out  = (const float*)d_in[5];
    const float* b_out  = (const float*)d_in[6];
    float* out = (float*)d_out;

    const int* srcI = ei;            // edge_index[0]
    const int* dstI = ei + N_EDGES;  // edge_index[1]

    char* ws = (char*)d_ws;
    float* dinv = (float*)ws;                                  // N floats
    float* h    = (float*)(ws + 524288);                       // N*HID
    float* h0   = h  + (size_t)N_NODES * HID;                  // N*HID
    float* agg  = h0 + (size_t)N_NODES * HID;                  // N*HID

    // gcn_norm
    deg_init<<<(N_NODES + 255) / 256, 256, 0, stream>>>(dinv);
    deg_count<<<(N_EDGES + 255) / 256, 256, 0, stream>>>(dstI, dinv);
    deg_to_dinv<<<(N_NODES + 255) / 256, 256, 0, stream>>>(dinv);

    // h = x @ w_in + b_in ; h0 = h
    in_gemm<<<N_NODES / 16, 256, 0, stream>>>(x, w_in, b_in, h, h0);

    for (int l = 0; l < NLAYERS; l++) {
        hipMemsetAsync(agg, 0, (size_t)N_NODES * HID * sizeof(float), stream);
        spmm_atomic<<<N_EDGES / 2, dim3(128, 2), 0, stream>>>(srcI, dstI, dinv, h, agg);
        float beta = logf(0.5f / (float)(l + 1) + 1.0f);
        layer_kernel<<<N_NODES / 16, 256, 0, stream>>>(
            agg, h0, dinv, conv_w + (size_t)l * HID * HID, h, 1.0f - beta, beta);
    }

    out_kernel<<<N_NODES / 4, 256, 0, stream>>>(h, w_out, b_out, out);
}

// Round 2
// 2605.504 us; speedup vs baseline: 2.7082x; 2.7082x over previous
//
#include <hip/hip_runtime.h>
#include <math.h>

#define N_NODES 100000
#define N_EDGES 1600000
#define F_IN    512
#define HID     128
#define NCLS    64
#define NLAYERS 8
#define NSCANB  ((N_NODES + 255) / 256)   // 391

// ================= CSR build =================

__global__ __launch_bounds__(256) void cnt_init(int* __restrict__ cnt) {
    int i = blockIdx.x * 256 + threadIdx.x;
    if (i < N_NODES) cnt[i] = 0;
}

__global__ __launch_bounds__(256) void cnt_count(const int* __restrict__ dst,
                                                 int* __restrict__ cnt) {
    int e = blockIdx.x * 256 + threadIdx.x;
    if (e < N_EDGES) atomicAdd(&cnt[dst[e]], 1);
}

__global__ __launch_bounds__(256) void make_dinv(const int* __restrict__ cnt,
                                                 float* __restrict__ dinv) {
    int i = blockIdx.x * 256 + threadIdx.x;
    if (i < N_NODES) dinv[i] = rsqrtf((float)(cnt[i] + 1));  // +1 self-loop
}

// per-block inclusive scan
__global__ __launch_bounds__(256) void scan_block(const int* __restrict__ cnt,
                                                  int* __restrict__ partial,
                                                  int* __restrict__ bsum) {
    __shared__ int tmp[256];
    int t = threadIdx.x, i = blockIdx.x * 256 + t;
    int v = (i < N_NODES) ? cnt[i] : 0;
    tmp[t] = v;
    __syncthreads();
#pragma unroll
    for (int off = 1; off < 256; off <<= 1) {
        int add = (t >= off) ? tmp[t - off] : 0;
        __syncthreads();
        tmp[t] += add;
        __syncthreads();
    }
    if (i < N_NODES) partial[i] = tmp[t];
    if (t == 255) bsum[blockIdx.x] = tmp[255];
}

__global__ void scan_bsum(int* __restrict__ bsum) {
    if (threadIdx.x == 0 && blockIdx.x == 0) {
        int acc = 0;
        for (int i = 0; i < NSCANB; i++) { int v = bsum[i]; bsum[i] = acc; acc += v; }
    }
}

__global__ __launch_bounds__(256) void finalize_rowptr(const int* __restrict__ cnt,
                                                       const int* __restrict__ partial,
                                                       const int* __restrict__ bsum,
                                                       int* __restrict__ row_ptr,
                                                       int* __restrict__ cursor) {
    int i = blockIdx.x * 256 + threadIdx.x;
    if (i < N_NODES) {
        int ex = partial[i] - cnt[i] + bsum[blockIdx.x];  // exclusive
        row_ptr[i] = ex;
        cursor[i]  = ex;
        if (i == N_NODES - 1) row_ptr[N_NODES] = ex + cnt[i];
    }
}

__global__ __launch_bounds__(256) void scatter_edges(const int* __restrict__ srcI,
                                                     const int* __restrict__ dstI,
                                                     const float* __restrict__ dinv,
                                                     int* __restrict__ cursor,
                                                     int2* __restrict__ rec) {
    int e = blockIdx.x * 256 + threadIdx.x;
    if (e < N_EDGES) {
        int s = srcI[e], d = dstI[e];
        int pos = atomicAdd(&cursor[d], 1);
        rec[pos] = make_int2(s, __float_as_int(dinv[s] * dinv[d]));
    }
}

// ================= input GEMM: h = x @ w_in + b_in ; h0 = h =================

__global__ __launch_bounds__(256) void in_gemm(const float* __restrict__ x,
                                               const float* __restrict__ w,
                                               const float* __restrict__ b,
                                               float* __restrict__ h,
                                               float* __restrict__ h0) {
    __shared__ float xs[16][F_IN];
    int block0 = blockIdx.x * 16;
    int tid = threadIdx.x;

    const float4* xg = (const float4*)(x + (size_t)block0 * F_IN);
    float4* xs4 = (float4*)&xs[0][0];
#pragma unroll
    for (int i = 0; i < 8; i++) xs4[tid + 256 * i] = xg[tid + 256 * i];
    __syncthreads();

    int col = tid & 127;
    int rg  = tid >> 7;
    float acc[8];
    float bb = b[col];
#pragma unroll
    for (int r = 0; r < 8; r++) acc[r] = bb;

    for (int k = 0; k < F_IN; k += 4) {
        float w0 = w[(k + 0) * HID + col];
        float w1 = w[(k + 1) * HID + col];
        float w2 = w[(k + 2) * HID + col];
        float w3 = w[(k + 3) * HID + col];
#pragma unroll
        for (int r = 0; r < 8; r++) {
            float4 xv = *(const float4*)&xs[rg * 8 + r][k];
            acc[r] += xv.x * w0 + xv.y * w1 + xv.z * w2 + xv.w * w3;
        }
    }
#pragma unroll
    for (int r = 0; r < 8; r++) {
        size_t idx = (size_t)(block0 + rg * 8 + r) * HID + col;
        h[idx]  = acc[r];
        h0[idx] = acc[r];
    }
}

// ================= fused SpMM gather + residual mix =================
// 8 nodes/block, 32 lanes/node, lane = one float4 of the 128 features.
// s = 0.9*(gather + dinv^2*h) + 0.1*h0

__global__ __launch_bounds__(256) void spmm_fused(const int* __restrict__ row_ptr,
                                                  const int2* __restrict__ rec,
                                                  const float* __restrict__ dinv,
                                                  const float* __restrict__ h,
                                                  const float* __restrict__ h0,
                                                  float* __restrict__ s) {
    int node = blockIdx.x * 8 + (threadIdx.x >> 5);
    int lane = threadIdx.x & 31;
    const float4* h4 = (const float4*)h;

    int e0 = row_ptr[node], e1 = row_ptr[node + 1];
    float4 acc = make_float4(0.f, 0.f, 0.f, 0.f);
    for (int e = e0; e < e1; e++) {
        int2 r = rec[e];
        float v = __int_as_float(r.y);
        float4 hv = h4[(size_t)r.x * 32 + lane];
        acc.x += v * hv.x; acc.y += v * hv.y;
        acc.z += v * hv.z; acc.w += v * hv.w;
    }
    float dd = dinv[node];
    float d2 = dd * dd;
    size_t idx = (size_t)node * 32 + lane;
    float4 hv = h4[idx];
    float4 z  = ((const float4*)h0)[idx];
    float4 o;
    o.x = 0.9f * (acc.x + d2 * hv.x) + 0.1f * z.x;
    o.y = 0.9f * (acc.y + d2 * hv.y) + 0.1f * z.y;
    o.z = 0.9f * (acc.z + d2 * hv.z) + 0.1f * z.z;
    o.w = 0.9f * (acc.w + d2 * hv.w) + 0.1f * z.w;
    ((float4*)s)[idx] = o;
}

// ================= per-layer GEMM: h = elu((1-b)*s + b*(s @ W)) =================

__global__ __launch_bounds__(256) void layer_gemm(const float* __restrict__ s,
                                                  const float* __restrict__ W,
                                                  float* __restrict__ h,
                                                  float oneMinusBeta, float beta) {
    __shared__ float ss[16][HID];
    int block0 = blockIdx.x * 16;
    int tid = threadIdx.x;

    const float4* sg = (const float4*)(s + (size_t)block0 * HID);
    float4* ssv = (float4*)&ss[0][0];
#pragma unroll
    for (int i = 0; i < 2; i++) ssv[tid + 256 * i] = sg[tid + 256 * i];
    __syncthreads();

    int col = tid & 127;
    int rg  = tid >> 7;
    float acc[8] = {0.f, 0.f, 0.f, 0.f, 0.f, 0.f, 0.f, 0.f};

    for (int k = 0; k < HID; k += 4) {
        float w0 = W[(k + 0) * HID + col];
        float w1 = W[(k + 1) * HID + col];
        float w2 = W[(k + 2) * HID + col];
        float w3 = W[(k + 3) * HID + col];
#pragma unroll
        for (int r = 0; r < 8; r++) {
            float4 sv = *(const float4*)&ss[rg * 8 + r][k];
            acc[r] += sv.x * w0 + sv.y * w1 + sv.z * w2 + sv.w * w3;
        }
    }
#pragma unroll
    for (int r = 0; r < 8; r++) {
        int row = rg * 8 + r;
        float v = oneMinusBeta * ss[row][col] + beta * acc[r];
        v = (v > 0.f) ? v : (expf(v) - 1.0f);   // ELU
        h[(size_t)(block0 + row) * HID + col] = v;
    }
}

// ================= output: log_softmax(h @ w_out + b_out) =================

__global__ __launch_bounds__(256) void out_kernel(const float* __restrict__ h,
                                                  const float* __restrict__ w,
                                                  const float* __restrict__ b,
                                                  float* __restrict__ out) {
    int node = blockIdx.x * 4 + (threadIdx.x >> 6);
    int lane = threadIdx.x & 63;
    const float* hr = h + (size_t)node * HID;
    float acc = b[lane];
    for (int k = 0; k < HID; k++) acc += hr[k] * w[k * NCLS + lane];
    float m = acc;
#pragma unroll
    for (int off = 32; off; off >>= 1) m = fmaxf(m, __shfl_xor(m, off, 64));
    float ex = expf(acc - m);
    float ssum = ex;
#pragma unroll
    for (int off = 32; off; off >>= 1) ssum += __shfl_xor(ssum, off, 64);
    out[(size_t)node * NCLS + lane] = acc - m - logf(ssum);
}

// ================= launch =================

extern "C" void kernel_launch(void* const* d_in, const int* in_sizes, int n_in,
                              void* d_out, int out_size, void* d_ws, size_t ws_size,
                              hipStream_t stream) {
    const float* x      = (const float*)d_in[0];
    const int*   ei     = (const int*)  d_in[1];
    const float* w_in   = (const float*)d_in[2];
    const float* b_in   = (const float*)d_in[3];
    const float* conv_w = (const float*)d_in[4];
    const float* w_out  = (const float*)d_in[5];
    const float* b_out  = (const float*)d_in[6];
    float* out = (float*)d_out;

    const int* srcI = ei;            // edge_index[0]
    const int* dstI = ei + N_EDGES;  // edge_index[1]

    char* ws = (char*)d_ws;
    float* dinv    = (float*)(ws + 0x000000);             // N floats
    int*   cnt     = (int*)  (ws + 0x080000);             // N ints
    int*   partial = (int*)  (ws + 0x100000);             // N ints
    int*   bsum    = (int*)  (ws + 0x180000);             // NSCANB ints
    int*   row_ptr = (int*)  (ws + 0x190000);             // N+1 ints
    int*   cursor  = (int*)  (ws + 0x200000);             // N ints
    int2*  rec     = (int2*) (ws + 0x280000);             // E int2 (12.8 MB)
    float* h       = (float*)(ws + 0x1000000);            // N*HID (51.2 MB)
    float* h0      = h  + (size_t)N_NODES * HID;
    float* sbuf    = h0 + (size_t)N_NODES * HID;

    int gN = (N_NODES + 255) / 256;
    int gE = (N_EDGES + 255) / 256;

    // ---- CSR build + norm ----
    cnt_init<<<gN, 256, 0, stream>>>(cnt);
    cnt_count<<<gE, 256, 0, stream>>>(dstI, cnt);
    make_dinv<<<gN, 256, 0, stream>>>(cnt, dinv);
    scan_block<<<NSCANB, 256, 0, stream>>>(cnt, partial, bsum);
    scan_bsum<<<1, 64, 0, stream>>>(bsum);
    finalize_rowptr<<<NSCANB, 256, 0, stream>>>(cnt, partial, bsum, row_ptr, cursor);
    scatter_edges<<<gE, 256, 0, stream>>>(srcI, dstI, dinv, cursor, rec);

    // ---- dense input projection ----
    in_gemm<<<N_NODES / 16, 256, 0, stream>>>(x, w_in, b_in, h, h0);

    // ---- layers ----
    for (int l = 0; l < NLAYERS; l++) {
        spmm_fused<<<N_NODES / 8, 256, 0, stream>>>(row_ptr, rec, dinv, h, h0, sbuf);
        float beta = logf(0.5f / (float)(l + 1) + 1.0f);
        layer_gemm<<<N_NODES / 16, 256, 0, stream>>>(
            sbuf, conv_w + (size_t)l * HID * HID, h, 1.0f - beta, beta);
    }

    out_kernel<<<N_NODES / 4, 256, 0, stream>>>(h, w_out, b_out, out);
}

// Round 3
// 1948.809 us; speedup vs baseline: 3.6207x; 1.3370x over previous
//
#include <hip/hip_runtime.h>
#include <math.h>

#define N_NODES 100000
#define N_EDGES 1600000
#define F_IN    512
#define HID     128
#define NCLS    64
#define NLAYERS 8
#define NT      (N_NODES / 16)            // 6250 exact row-tiles of 16
#define NSCANB  ((N_NODES + 255) / 256)   // 391

typedef __attribute__((ext_vector_type(8))) short short8;
typedef __attribute__((ext_vector_type(4))) float float4v;

// ---- bf16 helpers (round-to-nearest-even) ----
__device__ inline unsigned short f2bf(float f) {
    unsigned int u = __float_as_uint(f);
    unsigned int r = u + 0x7fffu + ((u >> 16) & 1u);
    return (unsigned short)(r >> 16);
}
__device__ inline float bf2f(unsigned short h) {
    return __uint_as_float(((unsigned int)h) << 16);
}
__device__ inline uint4 pack8(const unsigned short* v) {
    uint4 u;
    u.x = (unsigned)v[0] | ((unsigned)v[1] << 16);
    u.y = (unsigned)v[2] | ((unsigned)v[3] << 16);
    u.z = (unsigned)v[4] | ((unsigned)v[5] << 16);
    u.w = (unsigned)v[6] | ((unsigned)v[7] << 16);
    return u;
}

// ================= CSR build (unchanged from R2) =================

__global__ __launch_bounds__(256) void cnt_init(int* __restrict__ cnt) {
    int i = blockIdx.x * 256 + threadIdx.x;
    if (i < N_NODES) cnt[i] = 0;
}
__global__ __launch_bounds__(256) void cnt_count(const int* __restrict__ dst,
                                                 int* __restrict__ cnt) {
    int e = blockIdx.x * 256 + threadIdx.x;
    if (e < N_EDGES) atomicAdd(&cnt[dst[e]], 1);
}
__global__ __launch_bounds__(256) void make_dinv(const int* __restrict__ cnt,
                                                 float* __restrict__ dinv) {
    int i = blockIdx.x * 256 + threadIdx.x;
    if (i < N_NODES) dinv[i] = rsqrtf((float)(cnt[i] + 1));
}
__global__ __launch_bounds__(256) void scan_block(const int* __restrict__ cnt,
                                                  int* __restrict__ partial,
                                                  int* __restrict__ bsum) {
    __shared__ int tmp[256];
    int t = threadIdx.x, i = blockIdx.x * 256 + t;
    int v = (i < N_NODES) ? cnt[i] : 0;
    tmp[t] = v;
    __syncthreads();
#pragma unroll
    for (int off = 1; off < 256; off <<= 1) {
        int add = (t >= off) ? tmp[t - off] : 0;
        __syncthreads();
        tmp[t] += add;
        __syncthreads();
    }
    if (i < N_NODES) partial[i] = tmp[t];
    if (t == 255) bsum[blockIdx.x] = tmp[255];
}
__global__ void scan_bsum(int* __restrict__ bsum) {
    if (threadIdx.x == 0 && blockIdx.x == 0) {
        int acc = 0;
        for (int i = 0; i < NSCANB; i++) { int v = bsum[i]; bsum[i] = acc; acc += v; }
    }
}
__global__ __launch_bounds__(256) void finalize_rowptr(const int* __restrict__ cnt,
                                                       const int* __restrict__ partial,
                                                       const int* __restrict__ bsum,
                                                       int* __restrict__ row_ptr,
                                                       int* __restrict__ cursor) {
    int i = blockIdx.x * 256 + threadIdx.x;
    if (i < N_NODES) {
        int ex = partial[i] - cnt[i] + bsum[blockIdx.x];
        row_ptr[i] = ex;
        cursor[i]  = ex;
        if (i == N_NODES - 1) row_ptr[N_NODES] = ex + cnt[i];
    }
}
__global__ __launch_bounds__(256) void scatter_edges(const int* __restrict__ srcI,
                                                     const int* __restrict__ dstI,
                                                     const float* __restrict__ dinv,
                                                     int* __restrict__ cursor,
                                                     int2* __restrict__ rec) {
    int e = blockIdx.x * 256 + threadIdx.x;
    if (e < N_EDGES) {
        int s = srcI[e], d = dstI[e];
        int pos = atomicAdd(&cursor[d], 1);
        rec[pos] = make_int2(s, __float_as_int(dinv[s] * dinv[d]));
    }
}

// ================= weight pre-conversion (one-time, tiny) =================
// w_in [512][128] -> packed b-frags: per (nt 0..7, c 0..15): 1024 ushorts:
//   [hi: lane*8+j][lo: 512 + lane*8+j], where k = c*32 + (lane>>4)*8 + j,
//   n = nt*16 + (lane&15).
__global__ __launch_bounds__(64) void conv_win(const float* __restrict__ w,
                                               unsigned short* __restrict__ wip) {
    int nt = blockIdx.x >> 4;
    int c  = blockIdx.x & 15;
    int lane = threadIdx.x;
    int n  = nt * 16 + (lane & 15);
    int kb = c * 32 + (lane >> 4) * 8;
    unsigned short hi[8], lo[8];
#pragma unroll
    for (int j = 0; j < 8; j++) {
        float v = w[(size_t)(kb + j) * HID + n];
        hi[j] = f2bf(v);
        lo[j] = f2bf(v - bf2f(hi[j]));
    }
    size_t base = ((size_t)nt * 16 + c) * 1024 + (size_t)lane * 8;
    *(uint4*)&wip[base]       = pack8(hi);
    *(uint4*)&wip[base + 512] = pack8(lo);
}

// W'_l = beta_l * conv_w[l] + (1-beta_l) * I, packed per (l, nt 0..7, c 0..3)
__global__ __launch_bounds__(64) void conv_wl(const float* __restrict__ cw,
                                              unsigned short* __restrict__ wlp) {
    int l  = blockIdx.x >> 5;
    int nt = (blockIdx.x >> 2) & 7;
    int c  = blockIdx.x & 3;
    int lane = threadIdx.x;
    float beta = logf(0.5f / (float)(l + 1) + 1.0f);
    int n  = nt * 16 + (lane & 15);
    int kb = c * 32 + (lane >> 4) * 8;
    const float* W = cw + (size_t)l * HID * HID;
    unsigned short hi[8], lo[8];
#pragma unroll
    for (int j = 0; j < 8; j++) {
        int k = kb + j;
        float v = beta * W[(size_t)k * HID + n] + ((k == n) ? (1.0f - beta) : 0.0f);
        hi[j] = f2bf(v);
        lo[j] = f2bf(v - bf2f(hi[j]));
    }
    size_t base = (((size_t)l * 8 + nt) * 4 + c) * 1024 + (size_t)lane * 8;
    *(uint4*)&wlp[base]       = pack8(hi);
    *(uint4*)&wlp[base + 512] = pack8(lo);
}

// ================= input GEMM (split-bf16 MFMA): h = x @ w_in + b =================
// 4 waves/block, each wave one 16-row tile x full 128 cols. K=512 in 16 chunks.
__global__ __launch_bounds__(256) void in_gemm_mfma(const float* __restrict__ x,
        const unsigned short* __restrict__ wip, const float* __restrict__ bias,
        unsigned short* __restrict__ hb, unsigned short* __restrict__ h0b) {
    __shared__ float tile[64][132];
    int wave = threadIdx.x >> 6;
    int lane = threadIdx.x & 63;
    int t = blockIdx.x * 4 + wave;
    int m = lane & 15, q = lane >> 4;

    if (t < NT) {
        float4v acc[8];
#pragma unroll
        for (int nt = 0; nt < 8; nt++) acc[nt] = (float4v){0.f, 0.f, 0.f, 0.f};
        const float* xr = x + (size_t)(t * 16 + m) * F_IN + q * 8;
        const short8* wp8 = (const short8*)wip;
        for (int c = 0; c < 16; c++) {
            float4 x0 = *(const float4*)(xr + c * 32);
            float4 x1 = *(const float4*)(xr + c * 32 + 4);
            float xv[8] = {x0.x, x0.y, x0.z, x0.w, x1.x, x1.y, x1.z, x1.w};
            short8 ahi, alo;
#pragma unroll
            for (int j = 0; j < 8; j++) {
                unsigned short h = f2bf(xv[j]);
                ahi[j] = (short)h;
                alo[j] = (short)f2bf(xv[j] - bf2f(h));
            }
#pragma unroll
            for (int nt = 0; nt < 8; nt++) {
                short8 bhi = wp8[(size_t)(nt * 16 + c) * 128 + lane];
                short8 blo = wp8[(size_t)(nt * 16 + c) * 128 + 64 + lane];
                acc[nt] = __builtin_amdgcn_mfma_f32_16x16x32_bf16(ahi, bhi, acc[nt], 0, 0, 0);
                acc[nt] = __builtin_amdgcn_mfma_f32_16x16x32_bf16(ahi, blo, acc[nt], 0, 0, 0);
                acc[nt] = __builtin_amdgcn_mfma_f32_16x16x32_bf16(alo, bhi, acc[nt], 0, 0, 0);
            }
        }
        // C/D layout: col = lane&15, row = (lane>>4)*4 + reg
#pragma unroll
        for (int nt = 0; nt < 8; nt++) {
            float bb = bias[nt * 16 + m];
#pragma unroll
            for (int r = 0; r < 4; r++)
                tile[wave * 16 + q * 4 + r][nt * 16 + m] = acc[nt][r] + bb;
        }
    }
    __syncthreads();

    int nl = threadIdx.x >> 2, part = threadIdx.x & 3;
    int node = blockIdx.x * 64 + nl;
    if (node < N_NODES) {
        const float* src = &tile[nl][part * 32];
        unsigned short tv[32];
#pragma unroll
        for (int j = 0; j < 32; j++) tv[j] = f2bf(src[j]);
        uint4* d1 = (uint4*)&hb [(size_t)node * HID + part * 32];
        uint4* d2 = (uint4*)&h0b[(size_t)node * HID + part * 32];
#pragma unroll
        for (int j = 0; j < 4; j++) { uint4 u = pack8(&tv[j * 8]); d1[j] = u; d2[j] = u; }
    }
}

// ================= SpMM gather + mix -> packed s (hi/lo) =================
// 512 threads = 16 nodes x 32 lanes; one full 16-row tile per block.
__global__ __launch_bounds__(512) void spmm_pack(const int* __restrict__ row_ptr,
        const int2* __restrict__ rec, const float* __restrict__ dinv,
        const unsigned short* __restrict__ hb, const unsigned short* __restrict__ h0b,
        unsigned short* __restrict__ sp) {
    __shared__ float st[16][132];
    int t = blockIdx.x;
    int g = threadIdx.x >> 5;
    int l = threadIdx.x & 31;
    int node = t * 16 + g;

    int e0 = row_ptr[node], e1 = row_ptr[node + 1];
    float a0 = 0.f, a1 = 0.f, a2 = 0.f, a3 = 0.f;
    for (int e = e0; e < e1; e++) {
        int2 r = rec[e];
        float v = __int_as_float(r.y);
        ushort4 hv = *(const ushort4*)(hb + (size_t)r.x * HID + l * 4);
        a0 += v * bf2f(hv.x); a1 += v * bf2f(hv.y);
        a2 += v * bf2f(hv.z); a3 += v * bf2f(hv.w);
    }
    float dd = dinv[node], d2 = dd * dd;
    ushort4 hv = *(const ushort4*)(hb  + (size_t)node * HID + l * 4);
    ushort4 zv = *(const ushort4*)(h0b + (size_t)node * HID + l * 4);
    float4 o;
    o.x = 0.9f * (a0 + d2 * bf2f(hv.x)) + 0.1f * bf2f(zv.x);
    o.y = 0.9f * (a1 + d2 * bf2f(hv.y)) + 0.1f * bf2f(zv.y);
    o.z = 0.9f * (a2 + d2 * bf2f(hv.z)) + 0.1f * bf2f(zv.z);
    o.w = 0.9f * (a3 + d2 * bf2f(hv.w)) + 0.1f * bf2f(zv.w);
    *(float4*)&st[g][l * 4] = o;
    __syncthreads();

    if (threadIdx.x < 256) {
        int c = threadIdx.x >> 6, lane = threadIdx.x & 63;
        int m = lane & 15, q = lane >> 4;
        unsigned short hi[8], lo[8];
#pragma unroll
        for (int j = 0; j < 8; j++) {
            float s = st[m][c * 32 + q * 8 + j];
            hi[j] = f2bf(s);
            lo[j] = f2bf(s - bf2f(hi[j]));
        }
        size_t base = ((size_t)t * 4 + c) * 1024 + (size_t)lane * 8;
        *(uint4*)&sp[base]       = pack8(hi);
        *(uint4*)&sp[base + 512] = pack8(lo);
    }
}

// ================= layer GEMM: h = elu(s @ W') (skip folded into W') =================
__global__ __launch_bounds__(256) void layer_gemm_mfma(const unsigned short* __restrict__ sp,
        const unsigned short* __restrict__ wlp, unsigned short* __restrict__ hb,
        float* __restrict__ hf, int storeF32) {
    __shared__ float tile[64][132];
    int wave = threadIdx.x >> 6;
    int lane = threadIdx.x & 63;
    int t = blockIdx.x * 4 + wave;
    int m = lane & 15, q = lane >> 4;

    if (t < NT) {
        float4v acc[8];
#pragma unroll
        for (int nt = 0; nt < 8; nt++) acc[nt] = (float4v){0.f, 0.f, 0.f, 0.f};
        const short8* sp8 = (const short8*)sp;
        const short8* wp8 = (const short8*)wlp;
#pragma unroll
        for (int c = 0; c < 4; c++) {
            short8 ahi = sp8[((size_t)t * 4 + c) * 128 + lane];
            short8 alo = sp8[((size_t)t * 4 + c) * 128 + 64 + lane];
#pragma unroll
            for (int nt = 0; nt < 8; nt++) {
                short8 bhi = wp8[(size_t)(nt * 4 + c) * 128 + lane];
                short8 blo = wp8[(size_t)(nt * 4 + c) * 128 + 64 + lane];
                acc[nt] = __builtin_amdgcn_mfma_f32_16x16x32_bf16(ahi, bhi, acc[nt], 0, 0, 0);
                acc[nt] = __builtin_amdgcn_mfma_f32_16x16x32_bf16(ahi, blo, acc[nt], 0, 0, 0);
                acc[nt] = __builtin_amdgcn_mfma_f32_16x16x32_bf16(alo, bhi, acc[nt], 0, 0, 0);
            }
        }
#pragma unroll
        for (int nt = 0; nt < 8; nt++) {
#pragma unroll
            for (int r = 0; r < 4; r++) {
                float v = acc[nt][r];
                v = (v > 0.f) ? v : (expf(v) - 1.0f);  // ELU
                tile[wave * 16 + q * 4 + r][nt * 16 + m] = v;
            }
        }
    }
    __syncthreads();

    int nl = threadIdx.x >> 2, part = threadIdx.x & 3;
    int node = blockIdx.x * 64 + nl;
    if (node < N_NODES) {
        const float* src = &tile[nl][part * 32];
        unsigned short tv[32];
#pragma unroll
        for (int j = 0; j < 32; j++) tv[j] = f2bf(src[j]);
        uint4* d1 = (uint4*)&hb[(size_t)node * HID + part * 32];
#pragma unroll
        for (int j = 0; j < 4; j++) d1[j] = pack8(&tv[j * 8]);
        if (storeF32) {
            float4* d2 = (float4*)&hf[(size_t)node * HID + part * 32];
#pragma unroll
            for (int j = 0; j < 8; j++) d2[j] = *(const float4*)(src + j * 4);
        }
    }
}

// ================= output: log_softmax(h @ w_out + b_out) =================
__global__ __launch_bounds__(256) void out_kernel(const float* __restrict__ h,
                                                  const float* __restrict__ w,
                                                  const float* __restrict__ b,
                                                  float* __restrict__ out) {
    int node = blockIdx.x * 4 + (threadIdx.x >> 6);
    int lane = threadIdx.x & 63;
    const float* hr = h + (size_t)node * HID;
    float acc = b[lane];
    for (int k = 0; k < HID; k++) acc += hr[k] * w[k * NCLS + lane];
    float mx = acc;
#pragma unroll
    for (int off = 32; off; off >>= 1) mx = fmaxf(mx, __shfl_xor(mx, off, 64));
    float ex = expf(acc - mx);
    float ssum = ex;
#pragma unroll
    for (int off = 32; off; off >>= 1) ssum += __shfl_xor(ssum, off, 64);
    out[(size_t)node * NCLS + lane] = acc - mx - logf(ssum);
}

// ================= launch =================

extern "C" void kernel_launch(void* const* d_in, const int* in_sizes, int n_in,
                              void* d_out, int out_size, void* d_ws, size_t ws_size,
                              hipStream_t stream) {
    const float* x      = (const float*)d_in[0];
    const int*   ei     = (const int*)  d_in[1];
    const float* w_in   = (const float*)d_in[2];
    const float* b_in   = (const float*)d_in[3];
    const float* conv_w = (const float*)d_in[4];
    const float* w_out  = (const float*)d_in[5];
    const float* b_out  = (const float*)d_in[6];
    float* out = (float*)d_out;

    const int* srcI = ei;
    const int* dstI = ei + N_EDGES;

    char* ws = (char*)d_ws;
    float* dinv    = (float*)(ws + 0x000000);
    int*   cnt     = (int*)  (ws + 0x080000);
    int*   partial = (int*)  (ws + 0x100000);
    int*   bsum    = (int*)  (ws + 0x180000);
    int*   row_ptr = (int*)  (ws + 0x190000);
    int*   cursor  = (int*)  (ws + 0x200000);
    int2*  rec     = (int2*) (ws + 0x280000);                  // 12.8 MB
    unsigned short* wip = (unsigned short*)(ws + 0xF00000);    // 256 KB
    unsigned short* wlp = (unsigned short*)(ws + 0xF40000);    // 512 KB
    unsigned short* hb  = (unsigned short*)(ws + 0x1000000);   // 25.6 MB
    unsigned short* h0b = hb + (size_t)N_NODES * HID;          // 25.6 MB
    unsigned short* sp  = h0b + (size_t)N_NODES * HID;         // 51.2 MB (hi/lo)
    float* hf = (float*)(sp + (size_t)N_NODES * HID * 2);      // 51.2 MB

    int gN = (N_NODES + 255) / 256;
    int gE = (N_EDGES + 255) / 256;

    cnt_init<<<gN, 256, 0, stream>>>(cnt);
    cnt_count<<<gE, 256, 0, stream>>>(dstI, cnt);
    make_dinv<<<gN, 256, 0, stream>>>(cnt, dinv);
    scan_block<<<NSCANB, 256, 0, stream>>>(cnt, partial, bsum);
    scan_bsum<<<1, 64, 0, stream>>>(bsum);
    finalize_rowptr<<<NSCANB, 256, 0, stream>>>(cnt, partial, bsum, row_ptr, cursor);
    scatter_edges<<<gE, 256, 0, stream>>>(srcI, dstI, dinv, cursor, rec);

    conv_win<<<128, 64, 0, stream>>>(w_in, wip);
    conv_wl<<<256, 64, 0, stream>>>(conv_w, wlp);

    in_gemm_mfma<<<(NT + 3) / 4, 256, 0, stream>>>(x, wip, b_in, hb, h0b);

    for (int l = 0; l < NLAYERS; l++) {
        spmm_pack<<<NT, 512, 0, stream>>>(row_ptr, rec, dinv, hb, h0b, sp);
        layer_gemm_mfma<<<(NT + 3) / 4, 256, 0, stream>>>(
            sp, wlp + (size_t)l * 32768, hb, hf, (l == NLAYERS - 1) ? 1 : 0);
    }

    out_kernel<<<N_NODES / 4, 256, 0, stream>>>(hf, w_out, b_out, out);
}

// Round 5
// 1398.083 us; speedup vs baseline: 5.0470x; 1.3939x over previous
//
#include <hip/hip_runtime.h>
#include <math.h>

#define N_NODES 100000
#define N_EDGES 1600000
#define F_IN    512
#define HID     128
#define NCLS    64
#define NLAYERS 8
#define NT      (N_NODES / 16)            // 6250 exact row-tiles of 16
#define NSCANB  ((N_NODES + 255) / 256)   // 391

typedef __attribute__((ext_vector_type(8))) short short8;
typedef __attribute__((ext_vector_type(4))) float float4v;

// ---- bf16 helpers (round-to-nearest-even) ----
__device__ inline unsigned short f2bf(float f) {
    unsigned int u = __float_as_uint(f);
    unsigned int r = u + 0x7fffu + ((u >> 16) & 1u);
    return (unsigned short)(r >> 16);
}
__device__ inline float bf2f(unsigned short h) {
    return __uint_as_float(((unsigned int)h) << 16);
}
__device__ inline uint4 pack8(const unsigned short* v) {
    uint4 u;
    u.x = (unsigned)v[0] | ((unsigned)v[1] << 16);
    u.y = (unsigned)v[2] | ((unsigned)v[3] << 16);
    u.z = (unsigned)v[4] | ((unsigned)v[5] << 16);
    u.w = (unsigned)v[6] | ((unsigned)v[7] << 16);
    return u;
}
// accumulate 8 bf16 (packed uint4, low/high order) * v into a[8]
__device__ inline void bf8_fma(float* a, uint4 u, float v) {
    a[0] += v * __uint_as_float(u.x << 16);
    a[1] += v * __uint_as_float(u.x & 0xffff0000u);
    a[2] += v * __uint_as_float(u.y << 16);
    a[3] += v * __uint_as_float(u.y & 0xffff0000u);
    a[4] += v * __uint_as_float(u.z << 16);
    a[5] += v * __uint_as_float(u.z & 0xffff0000u);
    a[6] += v * __uint_as_float(u.w << 16);
    a[7] += v * __uint_as_float(u.w & 0xffff0000u);
}
// split fp32 into hi/lo bf16 and store into vector elements j of ahi/alo
__device__ inline void split_into(short8& ahi, short8& alo, int j, float f) {
    unsigned short h = f2bf(f);
    ahi[j] = (short)h;
    alo[j] = (short)f2bf(f - bf2f(h));
}

// ================= CSR build =================

__global__ __launch_bounds__(256) void cnt_init(int* __restrict__ cnt) {
    int i = blockIdx.x * 256 + threadIdx.x;
    if (i < N_NODES) cnt[i] = 0;
}
__global__ __launch_bounds__(256) void cnt_count(const int* __restrict__ dst,
                                                 int* __restrict__ cnt) {
    int e = blockIdx.x * 256 + threadIdx.x;
    if (e < N_EDGES) atomicAdd(&cnt[dst[e]], 1);
}
__global__ __launch_bounds__(256) void make_dinv(const int* __restrict__ cnt,
                                                 float* __restrict__ dinv) {
    int i = blockIdx.x * 256 + threadIdx.x;
    if (i < N_NODES) dinv[i] = rsqrtf((float)(cnt[i] + 1));
}
__global__ __launch_bounds__(256) void scan_block(const int* __restrict__ cnt,
                                                  int* __restrict__ partial,
                                                  int* __restrict__ bsum) {
    __shared__ int tmp[256];
    int t = threadIdx.x, i = blockIdx.x * 256 + t;
    int v = (i < N_NODES) ? cnt[i] : 0;
    tmp[t] = v;
    __syncthreads();
#pragma unroll
    for (int off = 1; off < 256; off <<= 1) {
        int add = (t >= off) ? tmp[t - off] : 0;
        __syncthreads();
        tmp[t] += add;
        __syncthreads();
    }
    if (i < N_NODES) partial[i] = tmp[t];
    if (t == 255) bsum[blockIdx.x] = tmp[255];
}
__global__ void scan_bsum(int* __restrict__ bsum) {
    if (threadIdx.x == 0 && blockIdx.x == 0) {
        int acc = 0;
        for (int i = 0; i < NSCANB; i++) { int v = bsum[i]; bsum[i] = acc; acc += v; }
    }
}
__global__ __launch_bounds__(256) void finalize_rowptr(const int* __restrict__ cnt,
                                                       const int* __restrict__ partial,
                                                       const int* __restrict__ bsum,
                                                       int* __restrict__ row_ptr,
                                                       int* __restrict__ cursor) {
    int i = blockIdx.x * 256 + threadIdx.x;
    if (i < N_NODES) {
        int ex = partial[i] - cnt[i] + bsum[blockIdx.x];
        row_ptr[i] = ex;
        cursor[i]  = ex;
        if (i == N_NODES - 1) row_ptr[N_NODES] = ex + cnt[i];
    }
}
__global__ __launch_bounds__(256) void scatter_edges(const int* __restrict__ srcI,
                                                     const int* __restrict__ dstI,
                                                     const float* __restrict__ dinv,
                                                     int* __restrict__ cursor,
                                                     int2* __restrict__ rec) {
    int e = blockIdx.x * 256 + threadIdx.x;
    if (e < N_EDGES) {
        int s = srcI[e], d = dstI[e];
        int pos = atomicAdd(&cursor[d], 1);
        rec[pos] = make_int2(s, __float_as_int(dinv[s] * dinv[d]));
    }
}

// ================= weight pre-conversion (one-time, tiny) =================
// w_in [512][128] -> B-frags hi/lo per (nt 0..7, c 0..15)
__global__ __launch_bounds__(64) void conv_win(const float* __restrict__ w,
                                               unsigned short* __restrict__ wip) {
    int nt = blockIdx.x >> 4;
    int c  = blockIdx.x & 15;
    int lane = threadIdx.x;
    int n  = nt * 16 + (lane & 15);
    int kb = c * 32 + (lane >> 4) * 8;
    unsigned short hi[8], lo[8];
#pragma unroll
    for (int j = 0; j < 8; j++) {
        float v = w[(size_t)(kb + j) * HID + n];
        hi[j] = f2bf(v);
        lo[j] = f2bf(v - bf2f(hi[j]));
    }
    size_t base = ((size_t)nt * 16 + c) * 1024 + (size_t)lane * 8;
    *(uint4*)&wip[base]       = pack8(hi);
    *(uint4*)&wip[base + 512] = pack8(lo);
}

// W'_l = beta_l * conv_w[l] + (1-beta_l) * I per (l, nt 0..7, c 0..3)
__global__ __launch_bounds__(64) void conv_wl(const float* __restrict__ cw,
                                              unsigned short* __restrict__ wlp) {
    int l  = blockIdx.x >> 5;
    int nt = (blockIdx.x >> 2) & 7;
    int c  = blockIdx.x & 3;
    int lane = threadIdx.x;
    float beta = logf(0.5f / (float)(l + 1) + 1.0f);
    int n  = nt * 16 + (lane & 15);
    int kb = c * 32 + (lane >> 4) * 8;
    const float* W = cw + (size_t)l * HID * HID;
    unsigned short hi[8], lo[8];
#pragma unroll
    for (int j = 0; j < 8; j++) {
        int k = kb + j;
        float v = beta * W[(size_t)k * HID + n] + ((k == n) ? (1.0f - beta) : 0.0f);
        hi[j] = f2bf(v);
        lo[j] = f2bf(v - bf2f(hi[j]));
    }
    size_t base = (((size_t)l * 8 + nt) * 4 + c) * 1024 + (size_t)lane * 8;
    *(uint4*)&wlp[base]       = pack8(hi);
    *(uint4*)&wlp[base + 512] = pack8(lo);
}

// w_out [128][64] -> B-frags hi/lo per (nt 0..3, c 0..3)
__global__ __launch_bounds__(64) void conv_wout(const float* __restrict__ w,
                                                unsigned short* __restrict__ wop) {
    int nt = blockIdx.x >> 2;
    int c  = blockIdx.x & 3;
    int lane = threadIdx.x;
    int n  = nt * 16 + (lane & 15);
    int kb = c * 32 + (lane >> 4) * 8;
    unsigned short hi[8], lo[8];
#pragma unroll
    for (int j = 0; j < 8; j++) {
        float v = w[(size_t)(kb + j) * NCLS + n];
        hi[j] = f2bf(v);
        lo[j] = f2bf(v - bf2f(hi[j]));
    }
    size_t base = ((size_t)nt * 4 + c) * 1024 + (size_t)lane * 8;
    *(uint4*)&wop[base]       = pack8(hi);
    *(uint4*)&wop[base + 512] = pack8(lo);
}

// ================= input GEMM: h = x @ w_in + b (split-bf16 MFMA) =================
__global__ __launch_bounds__(256) void in_gemm_mfma(const float* __restrict__ x,
        const unsigned short* __restrict__ wip, const float* __restrict__ bias,
        unsigned short* __restrict__ hb, unsigned short* __restrict__ h0b) {
    __shared__ unsigned short tile[64][136];
    int wave = threadIdx.x >> 6;
    int lane = threadIdx.x & 63;
    int t = blockIdx.x * 4 + wave;
    int m = lane & 15, q = lane >> 4;

    if (t < NT) {
        float4v acc[8];
#pragma unroll
        for (int nt = 0; nt < 8; nt++) acc[nt] = (float4v){0.f, 0.f, 0.f, 0.f};
        const float* xr = x + (size_t)(t * 16 + m) * F_IN + q * 8;
        const short8* wp8 = (const short8*)wip;
        for (int c = 0; c < 16; c++) {
            float4 x0 = *(const float4*)(xr + c * 32);
            float4 x1 = *(const float4*)(xr + c * 32 + 4);
            short8 ahi, alo;
            split_into(ahi, alo, 0, x0.x); split_into(ahi, alo, 1, x0.y);
            split_into(ahi, alo, 2, x0.z); split_into(ahi, alo, 3, x0.w);
            split_into(ahi, alo, 4, x1.x); split_into(ahi, alo, 5, x1.y);
            split_into(ahi, alo, 6, x1.z); split_into(ahi, alo, 7, x1.w);
#pragma unroll
            for (int nt = 0; nt < 8; nt++) {
                short8 bhi = wp8[(size_t)(nt * 16 + c) * 128 + lane];
                short8 blo = wp8[(size_t)(nt * 16 + c) * 128 + 64 + lane];
                acc[nt] = __builtin_amdgcn_mfma_f32_16x16x32_bf16(ahi, bhi, acc[nt], 0, 0, 0);
                acc[nt] = __builtin_amdgcn_mfma_f32_16x16x32_bf16(ahi, blo, acc[nt], 0, 0, 0);
                acc[nt] = __builtin_amdgcn_mfma_f32_16x16x32_bf16(alo, bhi, acc[nt], 0, 0, 0);
            }
        }
        // C/D: col = lane&15 (m), row = q*4 + r
#pragma unroll
        for (int nt = 0; nt < 8; nt++) {
            float bb = bias[nt * 16 + m];
#pragma unroll
            for (int r = 0; r < 4; r++)
                tile[wave * 16 + q * 4 + r][nt * 16 + m] = f2bf(acc[nt][r] + bb);
        }
    }
    __syncthreads();

    int nl = threadIdx.x >> 2, part = threadIdx.x & 3;
    int node = blockIdx.x * 64 + nl;
    if (node < N_NODES) {
        uint4* d1 = (uint4*)&hb [(size_t)node * HID + part * 32];
        uint4* d2 = (uint4*)&h0b[(size_t)node * HID + part * 32];
#pragma unroll
        for (int j = 0; j < 4; j++) {
            uint4 u = *(uint4*)&tile[nl][part * 32 + j * 8];
            d1[j] = u; d2[j] = u;
        }
    }
}

// ================= SpMM gather + residual mix -> s (f32 row-major) =================
// One wave per node, 4 edges in flight (16 lanes x ushort8 each), unroll x2.
__global__ __launch_bounds__(256) void spmm_mix(const int* __restrict__ row_ptr,
        const int2* __restrict__ rec, const float* __restrict__ dinv,
        const unsigned short* __restrict__ hb, const unsigned short* __restrict__ h0b,
        float* __restrict__ sout) {
    int node = blockIdx.x * 4 + (threadIdx.x >> 6);
    int lane = threadIdx.x & 63;
    int quarter = lane >> 4;
    int fl = lane & 15;                 // features fl*8 .. fl*8+7
    int e0 = row_ptr[node], e1 = row_ptr[node + 1];
    float a[8] = {0.f, 0.f, 0.f, 0.f, 0.f, 0.f, 0.f, 0.f};

    int e = e0 + quarter;
    for (; e + 4 < e1; e += 8) {
        int2 r0 = rec[e];
        int2 r1 = rec[e + 4];
        uint4 u0 = *(const uint4*)(hb + (size_t)r0.x * HID + fl * 8);
        uint4 u1 = *(const uint4*)(hb + (size_t)r1.x * HID + fl * 8);
        bf8_fma(a, u0, __int_as_float(r0.y));
        bf8_fma(a, u1, __int_as_float(r1.y));
    }
    for (; e < e1; e += 4) {
        int2 r0 = rec[e];
        uint4 u0 = *(const uint4*)(hb + (size_t)r0.x * HID + fl * 8);
        bf8_fma(a, u0, __int_as_float(r0.y));
    }
#pragma unroll
    for (int j = 0; j < 8; j++) {
        a[j] += __shfl_xor(a[j], 16);
        a[j] += __shfl_xor(a[j], 32);
    }
    if (quarter == 0) {
        float dd = dinv[node], d2 = dd * dd;
        uint4 hv = *(const uint4*)(hb  + (size_t)node * HID + fl * 8);
        uint4 zv = *(const uint4*)(h0b + (size_t)node * HID + fl * 8);
        float hvf[8], zvf[8];
        hvf[0] = __uint_as_float(hv.x << 16); hvf[1] = __uint_as_float(hv.x & 0xffff0000u);
        hvf[2] = __uint_as_float(hv.y << 16); hvf[3] = __uint_as_float(hv.y & 0xffff0000u);
        hvf[4] = __uint_as_float(hv.z << 16); hvf[5] = __uint_as_float(hv.z & 0xffff0000u);
        hvf[6] = __uint_as_float(hv.w << 16); hvf[7] = __uint_as_float(hv.w & 0xffff0000u);
        zvf[0] = __uint_as_float(zv.x << 16); zvf[1] = __uint_as_float(zv.x & 0xffff0000u);
        zvf[2] = __uint_as_float(zv.y << 16); zvf[3] = __uint_as_float(zv.y & 0xffff0000u);
        zvf[4] = __uint_as_float(zv.z << 16); zvf[5] = __uint_as_float(zv.z & 0xffff0000u);
        zvf[6] = __uint_as_float(zv.w << 16); zvf[7] = __uint_as_float(zv.w & 0xffff0000u);
        float o[8];
#pragma unroll
        for (int j = 0; j < 8; j++)
            o[j] = 0.9f * (a[j] + d2 * hvf[j]) + 0.1f * zvf[j];
        float4* dst = (float4*)(sout + (size_t)node * HID + fl * 8);
        dst[0] = make_float4(o[0], o[1], o[2], o[3]);
        dst[1] = make_float4(o[4], o[5], o[6], o[7]);
    }
}

// ================= layer GEMM: h = elu(s @ W'), s read f32 row-major =================
__global__ __launch_bounds__(256) void layer_gemm_bf(const float* __restrict__ s,
        const unsigned short* __restrict__ wlp, unsigned short* __restrict__ hb) {
    __shared__ unsigned short tile[64][136];
    int wave = threadIdx.x >> 6;
    int lane = threadIdx.x & 63;
    int t = blockIdx.x * 4 + wave;
    int m = lane & 15, q = lane >> 4;

    if (t < NT) {
        float4v acc[8];
#pragma unroll
        for (int nt = 0; nt < 8; nt++) acc[nt] = (float4v){0.f, 0.f, 0.f, 0.f};
        const float* sr = s + (size_t)(t * 16 + m) * HID + q * 8;
        const short8* wp8 = (const short8*)wlp;
#pragma unroll
        for (int c = 0; c < 4; c++) {
            float4 x0 = *(const float4*)(sr + c * 32);
            float4 x1 = *(const float4*)(sr + c * 32 + 4);
            short8 ahi, alo;
            split_into(ahi, alo, 0, x0.x); split_into(ahi, alo, 1, x0.y);
            split_into(ahi, alo, 2, x0.z); split_into(ahi, alo, 3, x0.w);
            split_into(ahi, alo, 4, x1.x); split_into(ahi, alo, 5, x1.y);
            split_into(ahi, alo, 6, x1.z); split_into(ahi, alo, 7, x1.w);
#pragma unroll
            for (int nt = 0; nt < 8; nt++) {
                short8 bhi = wp8[(size_t)(nt * 4 + c) * 128 + lane];
                short8 blo = wp8[(size_t)(nt * 4 + c) * 128 + 64 + lane];
                acc[nt] = __builtin_amdgcn_mfma_f32_16x16x32_bf16(ahi, bhi, acc[nt], 0, 0, 0);
                acc[nt] = __builtin_amdgcn_mfma_f32_16x16x32_bf16(ahi, blo, acc[nt], 0, 0, 0);
                acc[nt] = __builtin_amdgcn_mfma_f32_16x16x32_bf16(alo, bhi, acc[nt], 0, 0, 0);
            }
        }
#pragma unroll
        for (int nt = 0; nt < 8; nt++) {
#pragma unroll
            for (int r = 0; r < 4; r++) {
                float v = acc[nt][r];
                v = (v > 0.f) ? v : (expf(v) - 1.0f);
                tile[wave * 16 + q * 4 + r][nt * 16 + m] = f2bf(v);
            }
        }
    }
    __syncthreads();

    int nl = threadIdx.x >> 2, part = threadIdx.x & 3;
    int node = blockIdx.x * 64 + nl;
    if (node < N_NODES) {
        uint4* d1 = (uint4*)&hb[(size_t)node * HID + part * 32];
#pragma unroll
        for (int j = 0; j < 4; j++) d1[j] = *(uint4*)&tile[nl][part * 32 + j * 8];
    }
}

// last layer: write f32 h directly from accumulators (keeps final precision)
__global__ __launch_bounds__(256) void layer_gemm_last(const float* __restrict__ s,
        const unsigned short* __restrict__ wlp, float* __restrict__ hf) {
    int wave = threadIdx.x >> 6;
    int lane = threadIdx.x & 63;
    int t = blockIdx.x * 4 + wave;
    int m = lane & 15, q = lane >> 4;
    if (t >= NT) return;

    float4v acc[8];
#pragma unroll
    for (int nt = 0; nt < 8; nt++) acc[nt] = (float4v){0.f, 0.f, 0.f, 0.f};
    const float* sr = s + (size_t)(t * 16 + m) * HID + q * 8;
    const short8* wp8 = (const short8*)wlp;
#pragma unroll
    for (int c = 0; c < 4; c++) {
        float4 x0 = *(const float4*)(sr + c * 32);
        float4 x1 = *(const float4*)(sr + c * 32 + 4);
        short8 ahi, alo;
        split_into(ahi, alo, 0, x0.x); split_into(ahi, alo, 1, x0.y);
        split_into(ahi, alo, 2, x0.z); split_into(ahi, alo, 3, x0.w);
        split_into(ahi, alo, 4, x1.x); split_into(ahi, alo, 5, x1.y);
        split_into(ahi, alo, 6, x1.z); split_into(ahi, alo, 7, x1.w);
#pragma unroll
        for (int nt = 0; nt < 8; nt++) {
            short8 bhi = wp8[(size_t)(nt * 4 + c) * 128 + lane];
            short8 blo = wp8[(size_t)(nt * 4 + c) * 128 + 64 + lane];
            acc[nt] = __builtin_amdgcn_mfma_f32_16x16x32_bf16(ahi, bhi, acc[nt], 0, 0, 0);
            acc[nt] = __builtin_amdgcn_mfma_f32_16x16x32_bf16(ahi, blo, acc[nt], 0, 0, 0);
            acc[nt] = __builtin_amdgcn_mfma_f32_16x16x32_bf16(alo, bhi, acc[nt], 0, 0, 0);
        }
    }
#pragma unroll
    for (int nt = 0; nt < 8; nt++) {
#pragma unroll
        for (int r = 0; r < 4; r++) {
            float v = acc[nt][r];
            v = (v > 0.f) ? v : (expf(v) - 1.0f);
            hf[(size_t)(t * 16 + q * 4 + r) * HID + nt * 16 + m] = v;
        }
    }
}

// ================= out GEMM + log_softmax (split-bf16 MFMA) =================
__global__ __launch_bounds__(256) void out_gemm(const float* __restrict__ hf,
        const unsigned short* __restrict__ wop, const float* __restrict__ bias,
        float* __restrict__ out) {
    int wave = threadIdx.x >> 6;
    int lane = threadIdx.x & 63;
    int t = blockIdx.x * 4 + wave;
    int m = lane & 15, q = lane >> 4;
    if (t >= NT) return;

    float4v acc[4];
#pragma unroll
    for (int nt = 0; nt < 4; nt++) acc[nt] = (float4v){0.f, 0.f, 0.f, 0.f};
    const float* hr = hf + (size_t)(t * 16 + m) * HID + q * 8;
    const short8* wp8 = (const short8*)wop;
#pragma unroll
    for (int c = 0; c < 4; c++) {
        float4 x0 = *(const float4*)(hr + c * 32);
        float4 x1 = *(const float4*)(hr + c * 32 + 4);
        short8 ahi, alo;
        split_into(ahi, alo, 0, x0.x); split_into(ahi, alo, 1, x0.y);
        split_into(ahi, alo, 2, x0.z); split_into(ahi, alo, 3, x0.w);
        split_into(ahi, alo, 4, x1.x); split_into(ahi, alo, 5, x1.y);
        split_into(ahi, alo, 6, x1.z); split_into(ahi, alo, 7, x1.w);
#pragma unroll
        for (int nt = 0; nt < 4; nt++) {
            short8 bhi = wp8[(size_t)(nt * 4 + c) * 128 + lane];
            short8 blo = wp8[(size_t)(nt * 4 + c) * 128 + 64 + lane];
            acc[nt] = __builtin_amdgcn_mfma_f32_16x16x32_bf16(ahi, bhi, acc[nt], 0, 0, 0);
            acc[nt] = __builtin_amdgcn_mfma_f32_16x16x32_bf16(ahi, blo, acc[nt], 0, 0, 0);
            acc[nt] = __builtin_amdgcn_mfma_f32_16x16x32_bf16(alo, bhi, acc[nt], 0, 0, 0);
        }
    }
    // logits in C layout: row = q*4+r, col = nt*16+m. Bias + log_softmax per row.
    float bn[4];
#pragma unroll
    for (int nt = 0; nt < 4; nt++) bn[nt] = bias[nt * 16 + m];
#pragma unroll
    for (int r = 0; r < 4; r++) {
        float v0 = acc[0][r] + bn[0], v1 = acc[1][r] + bn[1];
        float v2 = acc[2][r] + bn[2], v3 = acc[3][r] + bn[3];
        float mx = fmaxf(fmaxf(v0, v1), fmaxf(v2, v3));
#pragma unroll
        for (int msk = 1; msk < 16; msk <<= 1) mx = fmaxf(mx, __shfl_xor(mx, msk));
        float ssum = expf(v0 - mx) + expf(v1 - mx) + expf(v2 - mx) + expf(v3 - mx);
#pragma unroll
        for (int msk = 1; msk < 16; msk <<= 1) ssum += __shfl_xor(ssum, msk);
        float lg = mx + logf(ssum);
        size_t base = (size_t)(t * 16 + q * 4 + r) * NCLS + m;
        out[base]      = v0 - lg;
        out[base + 16] = v1 - lg;
        out[base + 32] = v2 - lg;
        out[base + 48] = v3 - lg;
    }
}

// ================= launch =================

extern "C" void kernel_launch(void* const* d_in, const int* in_sizes, int n_in,
                              void* d_out, int out_size, void* d_ws, size_t ws_size,
                              hipStream_t stream) {
    const float* x      = (const float*)d_in[0];
    const int*   ei     = (const int*)  d_in[1];
    const float* w_in   = (const float*)d_in[2];
    const float* b_in   = (const float*)d_in[3];
    const float* conv_w = (const float*)d_in[4];
    const float* w_out  = (const float*)d_in[5];
    const float* b_out  = (const float*)d_in[6];
    float* out = (float*)d_out;

    const int* srcI = ei;
    const int* dstI = ei + N_EDGES;

    char* ws = (char*)d_ws;
    float* dinv    = (float*)(ws + 0x000000);
    int*   cnt     = (int*)  (ws + 0x080000);
    int*   partial = (int*)  (ws + 0x100000);
    int*   bsum    = (int*)  (ws + 0x180000);
    int*   row_ptr = (int*)  (ws + 0x190000);
    int*   cursor  = (int*)  (ws + 0x200000);
    int2*  rec     = (int2*) (ws + 0x280000);                  // 12.8 MB
    unsigned short* wip = (unsigned short*)(ws + 0xF00000);    // 256 KB
    unsigned short* wlp = (unsigned short*)(ws + 0xF40000);    // 512 KB
    unsigned short* wop = (unsigned short*)(ws + 0xFC0000);    // 32 KB
    unsigned short* hb  = (unsigned short*)(ws + 0x1000000);   // 25.6 MB
    unsigned short* h0b = hb + (size_t)N_NODES * HID;          // 25.6 MB
    float* sbuf = (float*)(h0b + (size_t)N_NODES * HID);       // 51.2 MB
    float* hf   = sbuf + (size_t)N_NODES * HID;                // 51.2 MB

    int gN = (N_NODES + 255) / 256;
    int gE = (N_EDGES + 255) / 256;
    int gT = (NT + 3) / 4;

    cnt_init<<<gN, 256, 0, stream>>>(cnt);
    cnt_count<<<gE, 256, 0, stream>>>(dstI, cnt);
    make_dinv<<<gN, 256, 0, stream>>>(cnt, dinv);
    scan_block<<<NSCANB, 256, 0, stream>>>(cnt, partial, bsum);
    scan_bsum<<<1, 64, 0, stream>>>(bsum);
    finalize_rowptr<<<NSCANB, 256, 0, stream>>>(cnt, partial, bsum, row_ptr, cursor);
    scatter_edges<<<gE, 256, 0, stream>>>(srcI, dstI, dinv, cursor, rec);

    conv_win<<<128, 64, 0, stream>>>(w_in, wip);
    conv_wl<<<256, 64, 0, stream>>>(conv_w, wlp);
    conv_wout<<<16, 64, 0, stream>>>(w_out, wop);

    in_gemm_mfma<<<gT, 256, 0, stream>>>(x, wip, b_in, hb, h0b);

    for (int l = 0; l < NLAYERS; l++) {
        spmm_mix<<<N_NODES / 4, 256, 0, stream>>>(row_ptr, rec, dinv, hb, h0b, sbuf);
        const unsigned short* wl = wlp + (size_t)l * 32768;
        if (l < NLAYERS - 1)
            layer_gemm_bf<<<gT, 256, 0, stream>>>(sbuf, wl, hb);
        else
            layer_gemm_last<<<gT, 256, 0, stream>>>(sbuf, wl, hf);
    }

    out_gemm<<<gT, 256, 0, stream>>>(hf, wop, b_out, out);
}

// Round 6
// 1270.113 us; speedup vs baseline: 5.5555x; 1.1008x over previous
//
#include <hip/hip_runtime.h>
#include <math.h>

#define N_NODES 100000
#define N_EDGES 1600000
#define F_IN    512
#define HID     128
#define NCLS    64
#define NLAYERS 8
#define NT      (N_NODES / 16)            // 6250 exact row-tiles of 16
#define NSCANB  ((N_NODES + 255) / 256)   // 391

typedef __attribute__((ext_vector_type(8))) short short8;
typedef __attribute__((ext_vector_type(4))) float float4v;

// ---- bf16 helpers (round-to-nearest-even) ----
__device__ inline unsigned short f2bf(float f) {
    unsigned int u = __float_as_uint(f);
    unsigned int r = u + 0x7fffu + ((u >> 16) & 1u);
    return (unsigned short)(r >> 16);
}
__device__ inline float bf2f(unsigned short h) {
    return __uint_as_float(((unsigned int)h) << 16);
}
__device__ inline uint4 pack8(const unsigned short* v) {
    uint4 u;
    u.x = (unsigned)v[0] | ((unsigned)v[1] << 16);
    u.y = (unsigned)v[2] | ((unsigned)v[3] << 16);
    u.z = (unsigned)v[4] | ((unsigned)v[5] << 16);
    u.w = (unsigned)v[6] | ((unsigned)v[7] << 16);
    return u;
}
// accumulate 8 bf16 (packed uint4, low/high order) * v into a[8]
__device__ inline void bf8_fma(float* a, uint4 u, float v) {
    a[0] += v * __uint_as_float(u.x << 16);
    a[1] += v * __uint_as_float(u.x & 0xffff0000u);
    a[2] += v * __uint_as_float(u.y << 16);
    a[3] += v * __uint_as_float(u.y & 0xffff0000u);
    a[4] += v * __uint_as_float(u.z << 16);
    a[5] += v * __uint_as_float(u.z & 0xffff0000u);
    a[6] += v * __uint_as_float(u.w << 16);
    a[7] += v * __uint_as_float(u.w & 0xffff0000u);
}
// split fp32 into hi/lo bf16 and store into vector element j of ahi/alo
__device__ inline void split_into(short8& ahi, short8& alo, int j, float f) {
    unsigned short h = f2bf(f);
    ahi[j] = (short)h;
    alo[j] = (short)f2bf(f - bf2f(h));
}

// ================= CSR build =================

__global__ __launch_bounds__(256) void cnt_init(int* __restrict__ cnt) {
    int i = blockIdx.x * 256 + threadIdx.x;
    if (i < N_NODES) cnt[i] = 0;
}
__global__ __launch_bounds__(256) void cnt_count(const int* __restrict__ dst,
                                                 int* __restrict__ cnt) {
    int e = blockIdx.x * 256 + threadIdx.x;
    if (e < N_EDGES) atomicAdd(&cnt[dst[e]], 1);
}
__global__ __launch_bounds__(256) void make_dinv(const int* __restrict__ cnt,
                                                 float* __restrict__ dinv) {
    int i = blockIdx.x * 256 + threadIdx.x;
    if (i < N_NODES) dinv[i] = rsqrtf((float)(cnt[i] + 1));
}
__global__ __launch_bounds__(256) void scan_block(const int* __restrict__ cnt,
                                                  int* __restrict__ partial,
                                                  int* __restrict__ bsum) {
    __shared__ int tmp[256];
    int t = threadIdx.x, i = blockIdx.x * 256 + t;
    int v = (i < N_NODES) ? cnt[i] : 0;
    tmp[t] = v;
    __syncthreads();
#pragma unroll
    for (int off = 1; off < 256; off <<= 1) {
        int add = (t >= off) ? tmp[t - off] : 0;
        __syncthreads();
        tmp[t] += add;
        __syncthreads();
    }
    if (i < N_NODES) partial[i] = tmp[t];
    if (t == 255) bsum[blockIdx.x] = tmp[255];
}
__global__ void scan_bsum(int* __restrict__ bsum) {
    if (threadIdx.x == 0 && blockIdx.x == 0) {
        int acc = 0;
        for (int i = 0; i < NSCANB; i++) { int v = bsum[i]; bsum[i] = acc; acc += v; }
    }
}
__global__ __launch_bounds__(256) void finalize_rowptr(const int* __restrict__ cnt,
                                                       const int* __restrict__ partial,
                                                       const int* __restrict__ bsum,
                                                       int* __restrict__ row_ptr,
                                                       int* __restrict__ cursor) {
    int i = blockIdx.x * 256 + threadIdx.x;
    if (i < N_NODES) {
        int ex = partial[i] - cnt[i] + bsum[blockIdx.x];
        row_ptr[i] = ex;
        cursor[i]  = ex;
        if (i == N_NODES - 1) row_ptr[N_NODES] = ex + cnt[i];
    }
}
__global__ __launch_bounds__(256) void scatter_edges(const int* __restrict__ srcI,
                                                     const int* __restrict__ dstI,
                                                     const float* __restrict__ dinv,
                                                     int* __restrict__ cursor,
                                                     int2* __restrict__ rec) {
    int e = blockIdx.x * 256 + threadIdx.x;
    if (e < N_EDGES) {
        int s = srcI[e], d = dstI[e];
        int pos = atomicAdd(&cursor[d], 1);
        rec[pos] = make_int2(s, __float_as_int(dinv[s] * dinv[d]));
    }
}

// ================= weight pre-conversion =================
// Layout: chunk-major. wip chunk c (c=0..15) = 16 KB contiguous: 8 nt-frags of
// 1024 ushorts each (hi at [0,512), lo at [512,1024)), frag elem = lane*8+j.
__global__ __launch_bounds__(64) void conv_win(const float* __restrict__ w,
                                               unsigned short* __restrict__ wip) {
    int nt = blockIdx.x >> 4;
    int c  = blockIdx.x & 15;
    int lane = threadIdx.x;
    int n  = nt * 16 + (lane & 15);
    int kb = c * 32 + (lane >> 4) * 8;
    unsigned short hi[8], lo[8];
#pragma unroll
    for (int j = 0; j < 8; j++) {
        float v = w[(size_t)(kb + j) * HID + n];
        hi[j] = f2bf(v);
        lo[j] = f2bf(v - bf2f(hi[j]));
    }
    size_t base = ((size_t)c * 8 + nt) * 1024 + (size_t)lane * 8;
    *(uint4*)&wip[base]       = pack8(hi);
    *(uint4*)&wip[base + 512] = pack8(lo);
}

// W'_l = beta_l * conv_w[l] + (1-beta_l) * I ; chunk-major per layer (c=0..3)
__global__ __launch_bounds__(64) void conv_wl(const float* __restrict__ cw,
                                              unsigned short* __restrict__ wlp) {
    int l  = blockIdx.x >> 5;
    int nt = (blockIdx.x >> 2) & 7;
    int c  = blockIdx.x & 3;
    int lane = threadIdx.x;
    float beta = logf(0.5f / (float)(l + 1) + 1.0f);
    int n  = nt * 16 + (lane & 15);
    int kb = c * 32 + (lane >> 4) * 8;
    const float* W = cw + (size_t)l * HID * HID;
    unsigned short hi[8], lo[8];
#pragma unroll
    for (int j = 0; j < 8; j++) {
        int k = kb + j;
        float v = beta * W[(size_t)k * HID + n] + ((k == n) ? (1.0f - beta) : 0.0f);
        hi[j] = f2bf(v);
        lo[j] = f2bf(v - bf2f(hi[j]));
    }
    size_t base = (size_t)l * 32768 + ((size_t)c * 8 + nt) * 1024 + (size_t)lane * 8;
    *(uint4*)&wlp[base]       = pack8(hi);
    *(uint4*)&wlp[base + 512] = pack8(lo);
}

// w_out [128][64] -> B-frags hi/lo per (nt 0..3, c 0..3) (local layout, unstaged)
__global__ __launch_bounds__(64) void conv_wout(const float* __restrict__ w,
                                                unsigned short* __restrict__ wop) {
    int nt = blockIdx.x >> 2;
    int c  = blockIdx.x & 3;
    int lane = threadIdx.x;
    int n  = nt * 16 + (lane & 15);
    int kb = c * 32 + (lane >> 4) * 8;
    unsigned short hi[8], lo[8];
#pragma unroll
    for (int j = 0; j < 8; j++) {
        float v = w[(size_t)(kb + j) * NCLS + n];
        hi[j] = f2bf(v);
        lo[j] = f2bf(v - bf2f(hi[j]));
    }
    size_t base = ((size_t)nt * 4 + c) * 1024 + (size_t)lane * 8;
    *(uint4*)&wop[base]       = pack8(hi);
    *(uint4*)&wop[base + 512] = pack8(lo);
}

// ================= input GEMM: h = x @ w_in + b (LDS-staged weights) =================
__global__ __launch_bounds__(256) void in_gemm_mfma(const float* __restrict__ x,
        const unsigned short* __restrict__ wip, const float* __restrict__ bias,
        unsigned short* __restrict__ hb, unsigned short* __restrict__ h0b) {
    __shared__ unsigned short wlds[8192];      // 16 KB: one K-chunk of B-frags
    __shared__ unsigned short tile[64][136];   // 17 KB output staging
    int tid = threadIdx.x;
    int wave = tid >> 6, lane = tid & 63;
    int t = blockIdx.x * 4 + wave;
    int m = lane & 15, q = lane >> 4;
    int tc = (t < NT) ? t : (NT - 1);          // clamp for address safety

    const uint4* wg = (const uint4*)wip;       // chunk c at uint4 index c*1024
    uint4 pf0 = wg[tid];
    uint4 pf1 = wg[tid + 256];
    uint4 pf2 = wg[tid + 512];
    uint4 pf3 = wg[tid + 768];

    float4v acc[8];
#pragma unroll
    for (int nt = 0; nt < 8; nt++) acc[nt] = (float4v){0.f, 0.f, 0.f, 0.f};
    const float* xr = x + (size_t)(tc * 16 + m) * F_IN + q * 8;
    uint4* wl4 = (uint4*)wlds;

    for (int c = 0; c < 16; c++) {
        wl4[tid] = pf0; wl4[tid + 256] = pf1; wl4[tid + 512] = pf2; wl4[tid + 768] = pf3;
        __syncthreads();
        if (c < 15) {
            const uint4* wn = wg + (size_t)(c + 1) * 1024;
            pf0 = wn[tid]; pf1 = wn[tid + 256]; pf2 = wn[tid + 512]; pf3 = wn[tid + 768];
        }
        float4 x0 = *(const float4*)(xr + c * 32);
        float4 x1 = *(const float4*)(xr + c * 32 + 4);
        short8 ahi, alo;
        split_into(ahi, alo, 0, x0.x); split_into(ahi, alo, 1, x0.y);
        split_into(ahi, alo, 2, x0.z); split_into(ahi, alo, 3, x0.w);
        split_into(ahi, alo, 4, x1.x); split_into(ahi, alo, 5, x1.y);
        split_into(ahi, alo, 6, x1.z); split_into(ahi, alo, 7, x1.w);
#pragma unroll
        for (int nt = 0; nt < 8; nt++) {
            short8 bhi = *(short8*)&wlds[nt * 1024 + lane * 8];
            short8 blo = *(short8*)&wlds[nt * 1024 + 512 + lane * 8];
            acc[nt] = __builtin_amdgcn_mfma_f32_16x16x32_bf16(ahi, bhi, acc[nt], 0, 0, 0);
            acc[nt] = __builtin_amdgcn_mfma_f32_16x16x32_bf16(ahi, blo, acc[nt], 0, 0, 0);
            acc[nt] = __builtin_amdgcn_mfma_f32_16x16x32_bf16(alo, bhi, acc[nt], 0, 0, 0);
        }
        __syncthreads();
    }

    if (t < NT) {
#pragma unroll
        for (int nt = 0; nt < 8; nt++) {
            float bb = bias[nt * 16 + m];
#pragma unroll
            for (int r = 0; r < 4; r++)
                tile[wave * 16 + q * 4 + r][nt * 16 + m] = f2bf(acc[nt][r] + bb);
        }
    }
    __syncthreads();

    int nl = tid >> 2, part = tid & 3;
    int node = blockIdx.x * 64 + nl;
    if (node < N_NODES) {
        uint4* d1 = (uint4*)&hb [(size_t)node * HID + part * 32];
        uint4* d2 = (uint4*)&h0b[(size_t)node * HID + part * 32];
#pragma unroll
        for (int j = 0; j < 4; j++) {
            uint4 u = *(uint4*)&tile[nl][part * 32 + j * 8];
            d1[j] = u; d2[j] = u;
        }
    }
}

// ================= SpMM gather + residual mix -> s (f32 row-major) =================
// One wave per node; 4 quarters x 16 lanes; 4 gathers in flight per quarter.
__global__ __launch_bounds__(256) void spmm_mix(const int* __restrict__ row_ptr,
        const int2* __restrict__ rec, const float* __restrict__ dinv,
        const unsigned short* __restrict__ hb, const unsigned short* __restrict__ h0b,
        float* __restrict__ sout) {
    int node = blockIdx.x * 4 + (threadIdx.x >> 6);
    int lane = threadIdx.x & 63;
    int quarter = lane >> 4;
    int fl = lane & 15;                 // features fl*8 .. fl*8+7
    int e0 = row_ptr[node], e1 = row_ptr[node + 1];
    float a[8] = {0.f, 0.f, 0.f, 0.f, 0.f, 0.f, 0.f, 0.f};

    int e = e0 + quarter;
    for (; e + 12 < e1; e += 16) {
        int2 r0 = rec[e];
        int2 r1 = rec[e + 4];
        int2 r2 = rec[e + 8];
        int2 r3 = rec[e + 12];
        uint4 u0 = *(const uint4*)(hb + (size_t)r0.x * HID + fl * 8);
        uint4 u1 = *(const uint4*)(hb + (size_t)r1.x * HID + fl * 8);
        uint4 u2 = *(const uint4*)(hb + (size_t)r2.x * HID + fl * 8);
        uint4 u3 = *(const uint4*)(hb + (size_t)r3.x * HID + fl * 8);
        bf8_fma(a, u0, __int_as_float(r0.y));
        bf8_fma(a, u1, __int_as_float(r1.y));
        bf8_fma(a, u2, __int_as_float(r2.y));
        bf8_fma(a, u3, __int_as_float(r3.y));
    }
    for (; e + 4 < e1; e += 8) {
        int2 r0 = rec[e];
        int2 r1 = rec[e + 4];
        uint4 u0 = *(const uint4*)(hb + (size_t)r0.x * HID + fl * 8);
        uint4 u1 = *(const uint4*)(hb + (size_t)r1.x * HID + fl * 8);
        bf8_fma(a, u0, __int_as_float(r0.y));
        bf8_fma(a, u1, __int_as_float(r1.y));
    }
    for (; e < e1; e += 4) {
        int2 r0 = rec[e];
        uint4 u0 = *(const uint4*)(hb + (size_t)r0.x * HID + fl * 8);
        bf8_fma(a, u0, __int_as_float(r0.y));
    }
#pragma unroll
    for (int j = 0; j < 8; j++) {
        a[j] += __shfl_xor(a[j], 16);
        a[j] += __shfl_xor(a[j], 32);
    }
    if (quarter == 0) {
        float dd = dinv[node], d2 = dd * dd;
        uint4 hv = *(const uint4*)(hb  + (size_t)node * HID + fl * 8);
        uint4 zv = *(const uint4*)(h0b + (size_t)node * HID + fl * 8);
        float hvf[8], zvf[8];
        hvf[0] = __uint_as_float(hv.x << 16); hvf[1] = __uint_as_float(hv.x & 0xffff0000u);
        hvf[2] = __uint_as_float(hv.y << 16); hvf[3] = __uint_as_float(hv.y & 0xffff0000u);
        hvf[4] = __uint_as_float(hv.z << 16); hvf[5] = __uint_as_float(hv.z & 0xffff0000u);
        hvf[6] = __uint_as_float(hv.w << 16); hvf[7] = __uint_as_float(hv.w & 0xffff0000u);
        zvf[0] = __uint_as_float(zv.x << 16); zvf[1] = __uint_as_float(zv.x & 0xffff0000u);
        zvf[2] = __uint_as_float(zv.y << 16); zvf[3] = __uint_as_float(zv.y & 0xffff0000u);
        zvf[4] = __uint_as_float(zv.z << 16); zvf[5] = __uint_as_float(zv.z & 0xffff0000u);
        zvf[6] = __uint_as_float(zv.w << 16); zvf[7] = __uint_as_float(zv.w & 0xffff0000u);
        float o[8];
#pragma unroll
        for (int j = 0; j < 8; j++)
            o[j] = 0.9f * (a[j] + d2 * hvf[j]) + 0.1f * zvf[j];
        float4* dst = (float4*)(sout + (size_t)node * HID + fl * 8);
        dst[0] = make_float4(o[0], o[1], o[2], o[3]);
        dst[1] = make_float4(o[4], o[5], o[6], o[7]);
    }
}

// ================= layer GEMM: h = elu(s @ W') (LDS-staged weights) =================
__global__ __launch_bounds__(256) void layer_gemm_bf(const float* __restrict__ s,
        const unsigned short* __restrict__ wlp, unsigned short* __restrict__ hb) {
    __shared__ unsigned short wlds[8192];
    __shared__ unsigned short tile[64][136];
    int tid = threadIdx.x;
    int wave = tid >> 6, lane = tid & 63;
    int t = blockIdx.x * 4 + wave;
    int m = lane & 15, q = lane >> 4;
    int tc = (t < NT) ? t : (NT - 1);

    const uint4* wg = (const uint4*)wlp;
    uint4 pf0 = wg[tid];
    uint4 pf1 = wg[tid + 256];
    uint4 pf2 = wg[tid + 512];
    uint4 pf3 = wg[tid + 768];

    float4v acc[8];
#pragma unroll
    for (int nt = 0; nt < 8; nt++) acc[nt] = (float4v){0.f, 0.f, 0.f, 0.f};
    const float* sr = s + (size_t)(tc * 16 + m) * HID + q * 8;
    uint4* wl4 = (uint4*)wlds;

#pragma unroll
    for (int c = 0; c < 4; c++) {
        wl4[tid] = pf0; wl4[tid + 256] = pf1; wl4[tid + 512] = pf2; wl4[tid + 768] = pf3;
        __syncthreads();
        if (c < 3) {
            const uint4* wn = wg + (size_t)(c + 1) * 1024;
            pf0 = wn[tid]; pf1 = wn[tid + 256]; pf2 = wn[tid + 512]; pf3 = wn[tid + 768];
        }
        float4 x0 = *(const float4*)(sr + c * 32);
        float4 x1 = *(const float4*)(sr + c * 32 + 4);
        short8 ahi, alo;
        split_into(ahi, alo, 0, x0.x); split_into(ahi, alo, 1, x0.y);
        split_into(ahi, alo, 2, x0.z); split_into(ahi, alo, 3, x0.w);
        split_into(ahi, alo, 4, x1.x); split_into(ahi, alo, 5, x1.y);
        split_into(ahi, alo, 6, x1.z); split_into(ahi, alo, 7, x1.w);
#pragma unroll
        for (int nt = 0; nt < 8; nt++) {
            short8 bhi = *(short8*)&wlds[nt * 1024 + lane * 8];
            short8 blo = *(short8*)&wlds[nt * 1024 + 512 + lane * 8];
            acc[nt] = __builtin_amdgcn_mfma_f32_16x16x32_bf16(ahi, bhi, acc[nt], 0, 0, 0);
            acc[nt] = __builtin_amdgcn_mfma_f32_16x16x32_bf16(ahi, blo, acc[nt], 0, 0, 0);
            acc[nt] = __builtin_amdgcn_mfma_f32_16x16x32_bf16(alo, bhi, acc[nt], 0, 0, 0);
        }
        __syncthreads();
    }

    if (t < NT) {
#pragma unroll
        for (int nt = 0; nt < 8; nt++) {
#pragma unroll
            for (int r = 0; r < 4; r++) {
                float v = acc[nt][r];
                v = (v > 0.f) ? v : (expf(v) - 1.0f);
                tile[wave * 16 + q * 4 + r][nt * 16 + m] = f2bf(v);
            }
        }
    }
    __syncthreads();

    int nl = tid >> 2, part = tid & 3;
    int node = blockIdx.x * 64 + nl;
    if (node < N_NODES) {
        uint4* d1 = (uint4*)&hb[(size_t)node * HID + part * 32];
#pragma unroll
        for (int j = 0; j < 4; j++) d1[j] = *(uint4*)&tile[nl][part * 32 + j * 8];
    }
}

// last layer: write f32 h directly from accumulators (chunk-major wlp layout)
__global__ __launch_bounds__(256) void layer_gemm_last(const float* __restrict__ s,
        const unsigned short* __restrict__ wlp, float* __restrict__ hf) {
    int wave = threadIdx.x >> 6;
    int lane = threadIdx.x & 63;
    int t = blockIdx.x * 4 + wave;
    int m = lane & 15, q = lane >> 4;
    if (t >= NT) return;

    float4v acc[8];
#pragma unroll
    for (int nt = 0; nt < 8; nt++) acc[nt] = (float4v){0.f, 0.f, 0.f, 0.f};
    const float* sr = s + (size_t)(t * 16 + m) * HID + q * 8;
    const short8* wp8 = (const short8*)wlp;
#pragma unroll
    for (int c = 0; c < 4; c++) {
        float4 x0 = *(const float4*)(sr + c * 32);
        float4 x1 = *(const float4*)(sr + c * 32 + 4);
        short8 ahi, alo;
        split_into(ahi, alo, 0, x0.x); split_into(ahi, alo, 1, x0.y);
        split_into(ahi, alo, 2, x0.z); split_into(ahi, alo, 3, x0.w);
        split_into(ahi, alo, 4, x1.x); split_into(ahi, alo, 5, x1.y);
        split_into(ahi, alo, 6, x1.z); split_into(ahi, alo, 7, x1.w);
#pragma unroll
        for (int nt = 0; nt < 8; nt++) {
            short8 bhi = wp8[(size_t)(c * 8 + nt) * 128 + lane];
            short8 blo = wp8[(size_t)(c * 8 + nt) * 128 + 64 + lane];
            acc[nt] = __builtin_amdgcn_mfma_f32_16x16x32_bf16(ahi, bhi, acc[nt], 0, 0, 0);
            acc[nt] = __builtin_amdgcn_mfma_f32_16x16x32_bf16(ahi, blo, acc[nt], 0, 0, 0);
            acc[nt] = __builtin_amdgcn_mfma_f32_16x16x32_bf16(alo, bhi, acc[nt], 0, 0, 0);
        }
    }
#pragma unroll
    for (int nt = 0; nt < 8; nt++) {
#pragma unroll
        for (int r = 0; r < 4; r++) {
            float v = acc[nt][r];
            v = (v > 0.f) ? v : (expf(v) - 1.0f);
            hf[(size_t)(t * 16 + q * 4 + r) * HID + nt * 16 + m] = v;
        }
    }
}

// ================= out GEMM + log_softmax (split-bf16 MFMA) =================
__global__ __launch_bounds__(256) void out_gemm(const float* __restrict__ hf,
        const unsigned short* __restrict__ wop, const float* __restrict__ bias,
        float* __restrict__ out) {
    int wave = threadIdx.x >> 6;
    int lane = threadIdx.x & 63;
    int t = blockIdx.x * 4 + wave;
    int m = lane & 15, q = lane >> 4;
    if (t >= NT) return;

    float4v acc[4];
#pragma unroll
    for (int nt = 0; nt < 4; nt++) acc[nt] = (float4v){0.f, 0.f, 0.f, 0.f};
    const float* hr = hf + (size_t)(t * 16 + m) * HID + q * 8;
    const short8* wp8 = (const short8*)wop;
#pragma unroll
    for (int c = 0; c < 4; c++) {
        float4 x0 = *(const float4*)(hr + c * 32);
        float4 x1 = *(const float4*)(hr + c * 32 + 4);
        short8 ahi, alo;
        split_into(ahi, alo, 0, x0.x); split_into(ahi, alo, 1, x0.y);
        split_into(ahi, alo, 2, x0.z); split_into(ahi, alo, 3, x0.w);
        split_into(ahi, alo, 4, x1.x); split_into(ahi, alo, 5, x1.y);
        split_into(ahi, alo, 6, x1.z); split_into(ahi, alo, 7, x1.w);
#pragma unroll
        for (int nt = 0; nt < 4; nt++) {
            short8 bhi = wp8[(size_t)(nt * 4 + c) * 128 + lane];
            short8 blo = wp8[(size_t)(nt * 4 + c) * 128 + 64 + lane];
            acc[nt] = __builtin_amdgcn_mfma_f32_16x16x32_bf16(ahi, bhi, acc[nt], 0, 0, 0);
            acc[nt] = __builtin_amdgcn_mfma_f32_16x16x32_bf16(ahi, blo, acc[nt], 0, 0, 0);
            acc[nt] = __builtin_amdgcn_mfma_f32_16x16x32_bf16(alo, bhi, acc[nt], 0, 0, 0);
        }
    }
    float bn[4];
#pragma unroll
    for (int nt = 0; nt < 4; nt++) bn[nt] = bias[nt * 16 + m];
#pragma unroll
    for (int r = 0; r < 4; r++) {
        float v0 = acc[0][r] + bn[0], v1 = acc[1][r] + bn[1];
        float v2 = acc[2][r] + bn[2], v3 = acc[3][r] + bn[3];
        float mx = fmaxf(fmaxf(v0, v1), fmaxf(v2, v3));
#pragma unroll
        for (int msk = 1; msk < 16; msk <<= 1) mx = fmaxf(mx, __shfl_xor(mx, msk));
        float ssum = expf(v0 - mx) + expf(v1 - mx) + expf(v2 - mx) + expf(v3 - mx);
#pragma unroll
        for (int msk = 1; msk < 16; msk <<= 1) ssum += __shfl_xor(ssum, msk);
        float lg = mx + logf(ssum);
        size_t base = (size_t)(t * 16 + q * 4 + r) * NCLS + m;
        out[base]      = v0 - lg;
        out[base + 16] = v1 - lg;
        out[base + 32] = v2 - lg;
        out[base + 48] = v3 - lg;
    }
}

// ================= launch =================

extern "C" void kernel_launch(void* const* d_in, const int* in_sizes, int n_in,
                              void* d_out, int out_size, void* d_ws, size_t ws_size,
                              hipStream_t stream) {
    const float* x      = (const float*)d_in[0];
    const int*   ei     = (const int*)  d_in[1];
    const float* w_in   = (const float*)d_in[2];
    const float* b_in   = (const float*)d_in[3];
    const float* conv_w = (const float*)d_in[4];
    const float* w_out  = (const float*)d_in[5];
    const float* b_out  = (const float*)d_in[6];
    float* out = (float*)d_out;

    const int* srcI = ei;
    const int* dstI = ei + N_EDGES;

    char* ws = (char*)d_ws;
    float* dinv    = (float*)(ws + 0x000000);
    int*   cnt     = (int*)  (ws + 0x080000);
    int*   partial = (int*)  (ws + 0x100000);
    int*   bsum    = (int*)  (ws + 0x180000);
    int*   row_ptr = (int*)  (ws + 0x190000);
    int*   cursor  = (int*)  (ws + 0x200000);
    int2*  rec     = (int2*) (ws + 0x280000);                  // 12.8 MB
    unsigned short* wip = (unsigned short*)(ws + 0xF00000);    // 256 KB
    unsigned short* wlp = (unsigned short*)(ws + 0xF40000);    // 512 KB
    unsigned short* wop = (unsigned short*)(ws + 0xFC0000);    // 32 KB
    unsigned short* hb  = (unsigned short*)(ws + 0x1000000);   // 25.6 MB
    unsigned short* h0b = hb + (size_t)N_NODES * HID;          // 25.6 MB
    float* sbuf = (float*)(h0b + (size_t)N_NODES * HID);       // 51.2 MB
    float* hf   = sbuf + (size_t)N_NODES * HID;                // 51.2 MB

    int gN = (N_NODES + 255) / 256;
    int gE = (N_EDGES + 255) / 256;
    int gT = (NT + 3) / 4;

    cnt_init<<<gN, 256, 0, stream>>>(cnt);
    cnt_count<<<gE, 256, 0, stream>>>(dstI, cnt);
    make_dinv<<<gN, 256, 0, stream>>>(cnt, dinv);
    scan_block<<<NSCANB, 256, 0, stream>>>(cnt, partial, bsum);
    scan_bsum<<<1, 64, 0, stream>>>(bsum);
    finalize_rowptr<<<NSCANB, 256, 0, stream>>>(cnt, partial, bsum, row_ptr, cursor);
    scatter_edges<<<gE, 256, 0, stream>>>(srcI, dstI, dinv, cursor, rec);

    conv_win<<<128, 64, 0, stream>>>(w_in, wip);
    conv_wl<<<256, 64, 0, stream>>>(conv_w, wlp);
    conv_wout<<<16, 64, 0, stream>>>(w_out, wop);

    in_gemm_mfma<<<gT, 256, 0, stream>>>(x, wip, b_in, hb, h0b);

    for (int l = 0; l < NLAYERS; l++) {
        spmm_mix<<<N_NODES / 4, 256, 0, stream>>>(row_ptr, rec, dinv, hb, h0b, sbuf);
        const unsigned short* wl = wlp + (size_t)l * 32768;
        if (l < NLAYERS - 1)
            layer_gemm_bf<<<gT, 256, 0, stream>>>(sbuf, wl, hb);
        else
            layer_gemm_last<<<gT, 256, 0, stream>>>(sbuf, wl, hf);
    }

    out_gemm<<<gT, 256, 0, stream>>>(hf, wop, b_out, out);
}